// Round 17
// baseline (94.171 us; speedup 1.0000x reference)
//
#include <hip/hip_runtime.h>

#define IMG 28
#define FLATK 784     // 28*28
#define OHW 26
#define FLAT 676      // 26*26
#define HID 100
#define NCLS 10
#define KP 800        // K padded (logical k 0..799; 784..799 zero in B)
#define BM 256        // rows per block (8 waves x 32 rows, mf=2)
#define BSTRIDE 808   // LDS B row stride in bf16 (800 + 8 pad)

typedef __attribute__((ext_vector_type(8))) short bfrag;   // 8 bf16 (4 VGPR)
typedef __attribute__((ext_vector_type(4))) float f32x4;
typedef __attribute__((ext_vector_type(4))) unsigned int u32x4;

__device__ __forceinline__ unsigned short f2bf(float f) {
    unsigned u = __float_as_uint(f);
    u = (u + 0x7fffu + ((u >> 16) & 1u)) >> 16;   // RNE
    return (unsigned short)u;
}

// Kernel 1: fold conv into fc1 -> bf16 W1eff [128 n][800 k] (zero-padded),
// and w2 -> bf16 [16 n][128 k] (zero-padded). (unchanged)
__global__ void build_weights(const float* __restrict__ conv_w,
                              const float* __restrict__ w1,
                              const float* __restrict__ w2,
                              unsigned short* __restrict__ w1b,
                              unsigned short* __restrict__ w2b) {
    int idx = blockIdx.x * blockDim.x + threadIdx.x;
    if (idx < 128 * KP) {
        int n = idx / KP, k = idx - n * KP;
        float val = 0.f;
        if (n < HID && k < FLATK) {
            int qr = k / IMG, qc = k % IMG;
            #pragma unroll
            for (int i = 0; i < 3; ++i) {
                int r = qr - i;
                if (r < 0 || r >= OHW) continue;
                #pragma unroll
                for (int j = 0; j < 3; ++j) {
                    int c = qc - j;
                    if (c < 0 || c >= OHW) continue;
                    val += conv_w[i * 3 + j] * w1[n * FLAT + r * OHW + c];
                }
            }
        }
        w1b[idx] = f2bf(val);
    } else {
        int t = idx - 128 * KP;
        if (t < 16 * 128) {
            int n = t >> 7, k = t & 127;
            float v = (n < NCLS && k < HID) ? w2[n * HID + k] : 0.f;
            w2b[t] = f2bf(v);
        }
    }
}

// k-order: step S, slice khi covers logical k = khi*200 + S*8 + j (bijective
// over 0..799). A and B both use this formula -> no relayout. Lane's x-walk
// is sequential: +64 B per pair of steps, contiguous 800 B per quarter.

// pair-load: steps 2T,2T+1 -> 4 f32x4 (64 B contiguous) per row, 2 rows.
// Wrap any address whose 16 B would cross the 784-float row end: only
// khi=3 slices with logical k>=784 trigger, and B=0 there.
#define LOADP(PH, T) do {                                                      \
    int a0 = kq + (T) * 16, a1 = a0 + 4, a2 = a0 + 8, a3 = a0 + 12;            \
    if (a0 >= FLATK) a0 -= FLATK;                                              \
    if (a1 >= FLATK) a1 -= FLATK;                                              \
    if (a2 >= FLATK) a2 -= FLATK;                                              \
    if (a3 >= FLATK) a3 -= FLATK;                                              \
    pre[PH][0] = *(const f32x4*)(xr0 + a0);                                    \
    pre[PH][1] = *(const f32x4*)(xr0 + a1);                                    \
    pre[PH][2] = *(const f32x4*)(xr0 + a2);                                    \
    pre[PH][3] = *(const f32x4*)(xr0 + a3);                                    \
    pre[PH][4] = *(const f32x4*)(xr1 + a0);                                    \
    pre[PH][5] = *(const f32x4*)(xr1 + a1);                                    \
    pre[PH][6] = *(const f32x4*)(xr1 + a2);                                    \
    pre[PH][7] = *(const f32x4*)(xr1 + a3);                                    \
} while (0)

// consume step S (= 2T+H) from half H of pair-slot PH: cvt_pk -> 2 A-frags;
// 7 B ds_reads at the SAME logical-k offset; 14 MFMA.
#define COMPH(PH, H, S) do {                                                   \
    union { u32x4 u; bfrag b; } a0_, a1_;                                      \
    asm("v_cvt_pk_bf16_f32 %0, %1, %2" : "=v"(a0_.u.x) : "v"(pre[PH][(H)*2].x),   "v"(pre[PH][(H)*2].y)); \
    asm("v_cvt_pk_bf16_f32 %0, %1, %2" : "=v"(a0_.u.y) : "v"(pre[PH][(H)*2].z),   "v"(pre[PH][(H)*2].w)); \
    asm("v_cvt_pk_bf16_f32 %0, %1, %2" : "=v"(a0_.u.z) : "v"(pre[PH][(H)*2+1].x), "v"(pre[PH][(H)*2+1].y)); \
    asm("v_cvt_pk_bf16_f32 %0, %1, %2" : "=v"(a0_.u.w) : "v"(pre[PH][(H)*2+1].z), "v"(pre[PH][(H)*2+1].w)); \
    asm("v_cvt_pk_bf16_f32 %0, %1, %2" : "=v"(a1_.u.x) : "v"(pre[PH][(H)*2+4].x), "v"(pre[PH][(H)*2+4].y)); \
    asm("v_cvt_pk_bf16_f32 %0, %1, %2" : "=v"(a1_.u.y) : "v"(pre[PH][(H)*2+4].z), "v"(pre[PH][(H)*2+4].w)); \
    asm("v_cvt_pk_bf16_f32 %0, %1, %2" : "=v"(a1_.u.z) : "v"(pre[PH][(H)*2+5].x), "v"(pre[PH][(H)*2+5].y)); \
    asm("v_cvt_pk_bf16_f32 %0, %1, %2" : "=v"(a1_.u.w) : "v"(pre[PH][(H)*2+5].z), "v"(pre[PH][(H)*2+5].w)); \
    _Pragma("unroll")                                                          \
    for (int nt = 0; nt < 7; ++nt) {                                           \
        int n_ = (nt < 6) ? ((nt << 4) + r15) : (84 + r15);                    \
        const bfrag bw = *(const bfrag*)(Blds + (size_t)n_ * BSTRIDE           \
                                         + kq + (S) * 8);                      \
        acc0[nt] = __builtin_amdgcn_mfma_f32_16x16x32_bf16(a0_.b, bw, acc0[nt], 0, 0, 0); \
        acc1[nt] = __builtin_amdgcn_mfma_f32_16x16x32_bf16(a1_.b, bw, acc1[nt], 0, 0, 0); \
    }                                                                          \
} while (0)

// Kernel 2: R16 template (B in LDS, barrier-free, 8 waves x 32 rows, BM=256,
// grid=256 = 1 block/CU). Single change: k-order permutation + 64B pair-loads
// so each lane streams its x-quarter sequentially.
__global__ __launch_bounds__(512) void fused_fwd(
    const float* __restrict__ x,              // [65536][784] f32
    const unsigned short* __restrict__ w1b,   // [128][800] bf16
    const float* __restrict__ b1,             // [100]
    const unsigned short* __restrict__ w2b,   // [16][128] bf16
    const float* __restrict__ b2,             // [10]
    float* __restrict__ out)                  // [65536][10] f32
{
    __shared__ char smem[100 * BSTRIDE * 2] __attribute__((aligned(128)));  // 161600 B
    unsigned short* Blds = (unsigned short*)smem;

    const int tid  = threadIdx.x;
    const int lane = tid & 63;
    const int wv   = tid >> 6;       // 0..7
    const int r15  = lane & 15;
    const int khi  = lane >> 4;      // 0..3
    const int kq   = khi * 200;      // lane's contiguous x-quarter base (floats)
    const int row0 = blockIdx.x * BM;

    // stage B: w1b rows 0..99 (incl. zero k-pad 784..799) -> LDS, 16B units
    for (int i = tid; i < 100 * 100; i += 512) {
        int n = i / 100, kv = i - n * 100;
        *(bfrag*)(Blds + (size_t)n * BSTRIDE + (kv << 3)) =
            *(const bfrag*)(w1b + (size_t)n * KP + (kv << 3));
    }
    __syncthreads();

    // A rows: lane holds row r15 of mf0 slab and row 16+r15 of mf1 slab
    const float* xr0 = x + (size_t)(row0 + (wv << 5) + r15) * FLATK;
    const float* xr1 = xr0 + 16 * FLATK;

    f32x4 acc0[7], acc1[7];
    #pragma unroll
    for (int n = 0; n < 7; ++n) {
        acc0[n] = f32x4{0.f, 0.f, 0.f, 0.f};
        acc1[n] = f32x4{0.f, 0.f, 0.f, 0.f};
    }

    f32x4 pre[2][8];   // 2 pair-slots (literal indices only)

    LOADP(0, 0); LOADP(1, 1);

    COMPH(0, 0, 0);  COMPH(0, 1, 1);  LOADP(0, 2);
    COMPH(1, 0, 2);  COMPH(1, 1, 3);  LOADP(1, 3);
    COMPH(0, 0, 4);  COMPH(0, 1, 5);  LOADP(0, 4);
    COMPH(1, 0, 6);  COMPH(1, 1, 7);  LOADP(1, 5);
    COMPH(0, 0, 8);  COMPH(0, 1, 9);  LOADP(0, 6);
    COMPH(1, 0, 10); COMPH(1, 1, 11); LOADP(1, 7);
    COMPH(0, 0, 12); COMPH(0, 1, 13); LOADP(0, 8);
    COMPH(1, 0, 14); COMPH(1, 1, 15); LOADP(1, 9);
    COMPH(0, 0, 16); COMPH(0, 1, 17); LOADP(0, 10);
    COMPH(1, 0, 18); COMPH(1, 1, 19); LOADP(1, 11);
    COMPH(0, 0, 20); COMPH(0, 1, 21); LOADP(0, 12);
    COMPH(1, 0, 22); COMPH(1, 1, 23);
    COMPH(0, 0, 24);

    __syncthreads();   // B-LDS dead; alias H1 over it

    // epilogue 1: bias+relu -> bf16 h1 [256][136]; zero cols 100..127
    unsigned short (*H1)[136] = (unsigned short (*)[136])smem;
    for (int i = tid; i < 256 * 28; i += 512) {
        int r = i / 28, c = 100 + (i - (i / 28) * 28);
        H1[r][c] = 0;
    }
    #pragma unroll
    for (int nt = 0; nt < 7; ++nt) {
        int col = (nt < 6) ? ((nt << 4) + r15) : (84 + r15);
        bool wr = (nt < 6) || (col >= 96);
        float bias = (col < HID) ? b1[col] : 0.f;
        int rb0 = (wv << 5) + (khi << 2);
        if (wr) {
            #pragma unroll
            for (int q = 0; q < 4; ++q) {
                float v0 = acc0[nt][q] + bias;
                float v1 = acc1[nt][q] + bias;
                H1[rb0 + q][col]      = f2bf(fmaxf(v0, 0.f));
                H1[rb0 + 16 + q][col] = f2bf(fmaxf(v1, 0.f));
            }
        }
    }
    __syncthreads();

    // layer 2: 8 waves x 32 rows (mf=2) over K=128 (pads are exact zeros)
    f32x4 acc2[2] = {f32x4{0.f,0.f,0.f,0.f}, f32x4{0.f,0.f,0.f,0.f}};
    #pragma unroll
    for (int ks = 0; ks < 4; ++ks) {
        const bfrag bwv = *(const bfrag*)(w2b + r15 * 128 + (ks << 5) + (khi << 3));
        #pragma unroll
        for (int mf = 0; mf < 2; ++mf) {
            int r = (wv << 5) + (mf << 4) + r15;
            const bfrag ah = *(const bfrag*)&H1[r][(ks << 5) + (khi << 3)];
            acc2[mf] = __builtin_amdgcn_mfma_f32_16x16x32_bf16(ah, bwv, acc2[mf], 0, 0, 0);
        }
    }

    if (r15 < NCLS) {
        float bias2 = b2[r15];
        #pragma unroll
        for (int mf = 0; mf < 2; ++mf) {
            int rbase = row0 + (wv << 5) + (mf << 4) + (khi << 2);
            #pragma unroll
            for (int q = 0; q < 4; ++q)
                out[(size_t)(rbase + q) * NCLS + r15] = acc2[mf][q] + bias2;
        }
    }
}

extern "C" void kernel_launch(void* const* d_in, const int* in_sizes, int n_in,
                              void* d_out, int out_size, void* d_ws, size_t ws_size,
                              hipStream_t stream) {
    const float* x      = (const float*)d_in[0];
    const float* conv_w = (const float*)d_in[1];
    const float* w1     = (const float*)d_in[2];
    const float* b1     = (const float*)d_in[3];
    const float* w2     = (const float*)d_in[4];
    const float* b2     = (const float*)d_in[5];
    float* out = (float*)d_out;

    unsigned short* w1b = (unsigned short*)d_ws;   // 128*800*2 = 204.8 KB
    unsigned short* w2b = w1b + 128 * KP;          // 16*128*2  = 4 KB

    build_weights<<<(128 * KP + 16 * 128 + 255) / 256, 256, 0, stream>>>(conv_w, w1, w2, w1b, w2b);
    fused_fwd<<<65536 / BM, 512, 0, stream>>>(x, w1b, b1, w2b, b2, out);
}

// Round 18
// 48.553 us; speedup vs baseline: 1.9395x; 1.9395x over previous
//
#include <hip/hip_runtime.h>

#define IMG 28
#define FLATK 784     // 28*28
#define OHW 26
#define FLAT 676      // 26*26
#define HID 100
#define NCLS 10
#define KP 800        // K padded to 25*32 (784..799 zero in B)
#define BM 128        // rows per block (8 waves x 16 rows, mf=1)
#define BSTRIDE 328   // LDS B row stride in bf16 (320 cols + 8 pad)

typedef __attribute__((ext_vector_type(8))) short bfrag;   // 8 bf16 (4 VGPR)
typedef __attribute__((ext_vector_type(4))) float f32x4;
typedef __attribute__((ext_vector_type(4))) unsigned int u32x4;

__device__ __forceinline__ unsigned short f2bf(float f) {
    unsigned u = __float_as_uint(f);
    u = (u + 0x7fffu + ((u >> 16) & 1u)) >> 16;   // RNE
    return (unsigned short)u;
}

// Kernel 1: fold conv into fc1 -> bf16 W1eff [128 n][800 k] (zero-padded),
// and w2 -> bf16 [16 n][128 k] (zero-padded). (unchanged)
__global__ void build_weights(const float* __restrict__ conv_w,
                              const float* __restrict__ w1,
                              const float* __restrict__ w2,
                              unsigned short* __restrict__ w1b,
                              unsigned short* __restrict__ w2b) {
    int idx = blockIdx.x * blockDim.x + threadIdx.x;
    if (idx < 128 * KP) {
        int n = idx / KP, k = idx - n * KP;
        float val = 0.f;
        if (n < HID && k < FLATK) {
            int qr = k / IMG, qc = k % IMG;
            #pragma unroll
            for (int i = 0; i < 3; ++i) {
                int r = qr - i;
                if (r < 0 || r >= OHW) continue;
                #pragma unroll
                for (int j = 0; j < 3; ++j) {
                    int c = qc - j;
                    if (c < 0 || c >= OHW) continue;
                    val += conv_w[i * 3 + j] * w1[n * FLAT + r * OHW + c];
                }
            }
        }
        w1b[idx] = f2bf(val);
    } else {
        int t = idx - 128 * KP;
        if (t < 16 * 128) {
            int n = t >> 7, k = t & 127;
            float v = (n < NCLS && k < HID) ? w2[n * HID + k] : 0.f;
            w2b[t] = f2bf(v);
        }
    }
}

// load step S's A-fragment (one 16-row slab) into pre[PH]; PH,S literal.
// R14/R16-proven line-perfect pattern: lanes {r15,khi} cover full 128B lines.
#define LOADA(PH, S) do {                                                      \
    int k_ = (S) * 32 + (khi << 3);                                            \
    if (k_ >= FLATK) k_ -= FLATK;  /* S=24 pad lanes: in-row garbage, B=0 */   \
    pre[PH][0] = *(const f32x4*)(xr0 + k_);                                    \
    pre[PH][1] = *(const f32x4*)(xr0 + k_ + 4);                                \
} while (0)

// consume step S (phase-local step SL = S%10): cvt_pk -> 1 A-fragment;
// 7 B ds_reads from the phase-resident LDS B; 7 MFMA.
#define COMP(PH, S, SL) do {                                                   \
    union { u32x4 u; bfrag b; } a0_;                                           \
    asm("v_cvt_pk_bf16_f32 %0, %1, %2" : "=v"(a0_.u.x) : "v"(pre[PH][0].x), "v"(pre[PH][0].y)); \
    asm("v_cvt_pk_bf16_f32 %0, %1, %2" : "=v"(a0_.u.y) : "v"(pre[PH][0].z), "v"(pre[PH][0].w)); \
    asm("v_cvt_pk_bf16_f32 %0, %1, %2" : "=v"(a0_.u.z) : "v"(pre[PH][1].x), "v"(pre[PH][1].y)); \
    asm("v_cvt_pk_bf16_f32 %0, %1, %2" : "=v"(a0_.u.w) : "v"(pre[PH][1].z), "v"(pre[PH][1].w)); \
    _Pragma("unroll")                                                          \
    for (int nt = 0; nt < 7; ++nt) {                                           \
        int n_ = (nt < 6) ? ((nt << 4) + r15) : (84 + r15);                    \
        const bfrag bw = *(const bfrag*)(Blds + (size_t)n_ * BSTRIDE           \
                                         + (SL) * 32 + (khi << 3));            \
        acc0[nt] = __builtin_amdgcn_mfma_f32_16x16x32_bf16(a0_.b, bw, acc0[nt], 0, 0, 0); \
    }                                                                          \
} while (0)

// Kernel 2: B split into 3 k-phases (320/320/160 cols) resident in a 65.6 KB
// LDS buffer -> 2 blocks/CU -> 16 load-issuing waves/CU (2x R16) at identical
// traffic. 8 waves x 16 rows (mf=1), barrier-free within each phase.
__global__ __launch_bounds__(512, 4) void fused_fwd(
    const float* __restrict__ x,              // [65536][784] f32
    const unsigned short* __restrict__ w1b,   // [128][800] bf16
    const float* __restrict__ b1,             // [100]
    const unsigned short* __restrict__ w2b,   // [16][128] bf16
    const float* __restrict__ b2,             // [10]
    float* __restrict__ out)                  // [65536][10] f32
{
    __shared__ char smem[100 * BSTRIDE * 2] __attribute__((aligned(128)));  // 65600 B
    unsigned short* Blds = (unsigned short*)smem;

    const int tid  = threadIdx.x;
    const int lane = tid & 63;
    const int wv   = tid >> 6;       // 0..7
    const int r15  = lane & 15;
    const int khi  = lane >> 4;      // 0..3 (k-slice *8)
    const int row0 = blockIdx.x * BM;

    // stage phase p of B: cols [p*320, p*320+320) -> LDS (phase 2: 160 cols)
    auto stageB = [&](int p) {
        for (int i = tid; i < 100 * 40; i += 512) {
            int n = i / 40, u = i - (i / 40) * 40;
            int col = p * 320 + (u << 3);
            if (col < KP)
                *(bfrag*)(Blds + (size_t)n * BSTRIDE + (u << 3)) =
                    *(const bfrag*)(w1b + (size_t)n * KP + col);
        }
    };

    // A rows: lane holds row r15 of the wave's 16-row slab
    const float* xr0 = x + (size_t)(row0 + (wv << 4) + r15) * FLATK;

    f32x4 acc0[7];
    #pragma unroll
    for (int n = 0; n < 7; ++n) acc0[n] = f32x4{0.f, 0.f, 0.f, 0.f};

    f32x4 pre[3][2];   // depth-3 A ring (literal indices only)

    LOADA(0, 0); LOADA(1, 1); LOADA(2, 2);
    stageB(0);
    __syncthreads();

    COMP(0, 0, 0); LOADA(0, 3);  COMP(1, 1, 1); LOADA(1, 4);  COMP(2, 2, 2); LOADA(2, 5);
    COMP(0, 3, 3); LOADA(0, 6);  COMP(1, 4, 4); LOADA(1, 7);  COMP(2, 5, 5); LOADA(2, 8);
    COMP(0, 6, 6); LOADA(0, 9);  COMP(1, 7, 7); LOADA(1, 10); COMP(2, 8, 8); LOADA(2, 11);
    COMP(0, 9, 9); LOADA(0, 12);

    __syncthreads(); stageB(1); __syncthreads();

    COMP(1, 10, 0); LOADA(1, 13); COMP(2, 11, 1); LOADA(2, 14);
    COMP(0, 12, 2); LOADA(0, 15); COMP(1, 13, 3); LOADA(1, 16);
    COMP(2, 14, 4); LOADA(2, 17); COMP(0, 15, 5); LOADA(0, 18);
    COMP(1, 16, 6); LOADA(1, 19); COMP(2, 17, 7); LOADA(2, 20);
    COMP(0, 18, 8); LOADA(0, 21); COMP(1, 19, 9); LOADA(1, 22);

    __syncthreads(); stageB(2); __syncthreads();

    COMP(2, 20, 0); LOADA(2, 23); COMP(0, 21, 1); LOADA(0, 24); COMP(1, 22, 2);
    COMP(2, 23, 3); COMP(0, 24, 4);

    __syncthreads();   // B-LDS dead; alias H1 over it

    // epilogue 1: bias+relu -> bf16 h1 [128][136]; zero cols 100..127
    unsigned short (*H1)[136] = (unsigned short (*)[136])smem;
    for (int i = tid; i < 128 * 28; i += 512) {
        int r = i / 28, c = 100 + (i - (i / 28) * 28);
        H1[r][c] = 0;
    }
    #pragma unroll
    for (int nt = 0; nt < 7; ++nt) {
        int col = (nt < 6) ? ((nt << 4) + r15) : (84 + r15);
        bool wr = (nt < 6) || (col >= 96);
        float bias = (col < HID) ? b1[col] : 0.f;
        int rb0 = (wv << 4) + (khi << 2);
        if (wr) {
            #pragma unroll
            for (int q = 0; q < 4; ++q) {
                float v0 = acc0[nt][q] + bias;
                H1[rb0 + q][col] = f2bf(fmaxf(v0, 0.f));
            }
        }
    }
    __syncthreads();

    // layer 2: 8 waves x 16 rows over K=128 (pad cols/k are exact zeros)
    f32x4 acc2 = f32x4{0.f, 0.f, 0.f, 0.f};
    const int r2 = (wv << 4) + r15;
    #pragma unroll
    for (int ks = 0; ks < 4; ++ks) {
        const bfrag bwv = *(const bfrag*)(w2b + r15 * 128 + (ks << 5) + (khi << 3));
        const bfrag ah = *(const bfrag*)&H1[r2][(ks << 5) + (khi << 3)];
        acc2 = __builtin_amdgcn_mfma_f32_16x16x32_bf16(ah, bwv, acc2, 0, 0, 0);
    }

    if (r15 < NCLS) {
        float bias2 = b2[r15];
        int rbase = row0 + (wv << 4) + (khi << 2);
        #pragma unroll
        for (int q = 0; q < 4; ++q)
            out[(size_t)(rbase + q) * NCLS + r15] = acc2[q] + bias2;
    }
}

extern "C" void kernel_launch(void* const* d_in, const int* in_sizes, int n_in,
                              void* d_out, int out_size, void* d_ws, size_t ws_size,
                              hipStream_t stream) {
    const float* x      = (const float*)d_in[0];
    const float* conv_w = (const float*)d_in[1];
    const float* w1     = (const float*)d_in[2];
    const float* b1     = (const float*)d_in[3];
    const float* w2     = (const float*)d_in[4];
    const float* b2     = (const float*)d_in[5];
    float* out = (float*)d_out;

    unsigned short* w1b = (unsigned short*)d_ws;   // 128*800*2 = 204.8 KB
    unsigned short* w2b = w1b + 128 * KP;          // 16*128*2  = 4 KB

    build_weights<<<(128 * KP + 16 * 128 + 255) / 256, 256, 0, stream>>>(conv_w, w1, w2, w1b, w2b);
    fused_fwd<<<65536 / BM, 512, 0, stream>>>(x, w1b, b1, w2b, b2, out);
}